// Round 4
// baseline (1132.675 us; speedup 1.0000x reference)
//
#include <hip/hip_runtime.h>

#define D 32
#define K_CODES 8192
#define ROWS_PB 32
#define TPB 256
#define QSTRIDE 2048          // quadrant stride in k
#define JITERS 8              // K_CODES / (4 * TPB)

// Map float -> unsigned such that unsigned order == float order (all floats).
__device__ __forceinline__ unsigned sortkey(float f) {
    unsigned b = __float_as_uint(f);
    return b ^ ((unsigned)((int)b >> 31) | 0x80000000u);
}

__global__ __launch_bounds__(TPB, 2) void vq_main(
    const float* __restrict__ x, const float* __restrict__ cb,
    float* __restrict__ out, unsigned* __restrict__ minD,
    unsigned* __restrict__ used, float* __restrict__ mse_accum)
{
    __shared__ float4 xs4[ROWS_PB][8];           // 32 rows x 32 dims, b128-aligned
    __shared__ float xx[ROWS_PB];
    __shared__ unsigned tokS[ROWS_PB];
    __shared__ unsigned long long wbest[4][ROWS_PB];
    __shared__ float pp[4];

    const int tid = threadIdx.x;
    const long row0 = (long)blockIdx.x * ROWS_PB;

    // Stage 32 rows (4 KB) into LDS, coalesced float4.
    ((float4*)xs4)[tid] = ((const float4*)(x + row0 * D))[tid];
    __syncthreads();
    if (tid < ROWS_PB) {
        float s = 0.f;
        const float* xr = (const float*)xs4[tid];
        #pragma unroll
        for (int d = 0; d < D; ++d) s += xr[d] * xr[d];
        xx[tid] = s;
    }
    __syncthreads();

    // Per-row running best score / index (this thread's codes only).
    float bs[ROWS_PB];
    int   bi[ROWS_PB];
    #pragma unroll
    for (int r = 0; r < ROWS_PB; ++r) { bs[r] = -3.0e38f; bi[r] = 0; }

    const float4* cb4 = (const float4*)cb;

    for (int j = 0; j < JITERS; ++j) {
        const int k0 = tid + j * TPB;            // [0, 2048)
        // Load 4 codes (quadrants of k) into registers: 128 VGPRs.
        float4 c[4][8];
        #pragma unroll
        for (int q = 0; q < 4; ++q) {
            const float4* p = cb4 + (long)(k0 + q * QSTRIDE) * 8;
            #pragma unroll
            for (int w = 0; w < 8; ++w) c[q][w] = p[w];
        }
        float Cn[4];
        #pragma unroll
        for (int q = 0; q < 4; ++q) {
            float s = 0.f;
            #pragma unroll
            for (int w = 0; w < 8; ++w)
                s += c[q][w].x*c[q][w].x + c[q][w].y*c[q][w].y
                   + c[q][w].z*c[q][w].z + c[q][w].w*c[q][w].w;
            Cn[q] = s;
        }
        float md[4] = {3.0e38f, 3.0e38f, 3.0e38f, 3.0e38f};

        #pragma unroll
        for (int r = 0; r < ROWS_PB; ++r) {
            float dot0 = 0.f, dot1 = 0.f, dot2 = 0.f, dot3 = 0.f;
            #pragma unroll
            for (int w = 0; w < 8; ++w) {
                const float4 xv = xs4[r][w];     // uniform-address b128 broadcast
                dot0 += c[0][w].x*xv.x; dot0 += c[0][w].y*xv.y;
                dot0 += c[0][w].z*xv.z; dot0 += c[0][w].w*xv.w;
                dot1 += c[1][w].x*xv.x; dot1 += c[1][w].y*xv.y;
                dot1 += c[1][w].z*xv.z; dot1 += c[1][w].w*xv.w;
                dot2 += c[2][w].x*xv.x; dot2 += c[2][w].y*xv.y;
                dot2 += c[2][w].z*xv.z; dot2 += c[2][w].w*xv.w;
                dot3 += c[3][w].x*xv.x; dot3 += c[3][w].y*xv.y;
                dot3 += c[3][w].z*xv.z; dot3 += c[3][w].w*xv.w;
            }
            // score s = 2*x.c - ||c||^2 ; argmin dist == argmax s (||x||^2 common)
            const float s0 = 2.f*dot0 - Cn[0];
            const float s1 = 2.f*dot1 - Cn[1];
            const float s2 = 2.f*dot2 - Cn[2];
            const float s3 = 2.f*dot3 - Cn[3];
            // 4-way argmax tree; strict > prefers smaller k (k0<k1<k2<k3).
            float ma = s0; int ka = k0;
            if (s1 > ma) { ma = s1; ka = k0 + QSTRIDE; }
            float mb = s2; int kb = k0 + 2*QSTRIDE;
            if (s3 > mb) { mb = s3; kb = k0 + 3*QSTRIDE; }
            if (mb > ma) { ma = mb; ka = kb; }
            // cross-j update: exact ties must keep smallest k
            if (ma > bs[r] || (ma == bs[r] && ka < bi[r])) { bs[r] = ma; bi[r] = ka; }
            // entropy-loss per-code min distance (dist = ||x||^2 - s, always > 0)
            const float xxr = xx[r];
            md[0] = fminf(md[0], xxr - s0);
            md[1] = fminf(md[1], xxr - s1);
            md[2] = fminf(md[2], xxr - s2);
            md[3] = fminf(md[3], xxr - s3);
        }
        #pragma unroll
        for (int q = 0; q < 4; ++q)
            atomicMin(&minD[k0 + q * QSTRIDE], __float_as_uint(md[q]));
    }

    // Block-level per-row argmax reduce: pack to u64 once, shuffle tree, LDS across waves.
    const int lane = tid & 63;
    const int wid = tid >> 6;
    #pragma unroll
    for (int r = 0; r < ROWS_PB; ++r) {
        unsigned long long b =
            ((unsigned long long)sortkey(bs[r]) << 32) | (unsigned)(~bi[r]);
        #pragma unroll
        for (int off = 32; off > 0; off >>= 1) {
            unsigned long long o = __shfl_xor(b, off, 64);
            if (o > b) b = o;
        }
        if (lane == 0) wbest[wid][r] = b;
    }
    __syncthreads();
    if (tid < ROWS_PB) {
        unsigned long long b = wbest[0][tid];
        if (wbest[1][tid] > b) b = wbest[1][tid];
        if (wbest[2][tid] > b) b = wbest[2][tid];
        if (wbest[3][tid] > b) b = wbest[3][tid];
        unsigned tok = ~(unsigned)(b & 0xFFFFFFFFull);
        tokS[tid] = tok;
        used[tok] = 1u;   // benign race: all writers store 1
    }
    __syncthreads();

    // Emit emb (== straight-through output values) + fused MSE partial.
    float part = 0.f;
    #pragma unroll
    for (int i = tid; i < ROWS_PB * D; i += TPB) {
        int r = i >> 5, d = i & 31;
        float e = cb[(long)tokS[r] * D + d];
        out[(row0 + r) * D + d] = e;
        float dx = e - ((const float*)xs4[r])[d];
        part += dx * dx;
    }
    #pragma unroll
    for (int off = 32; off > 0; off >>= 1) part += __shfl_xor(part, off, 64);
    if (lane == 0) pp[wid] = part;
    __syncthreads();
    if (tid == 0) atomicAdd(mse_accum, pp[0] + pp[1] + pp[2] + pp[3]);
}

__global__ __launch_bounds__(TPB) void vq_finish(
    const unsigned* __restrict__ minD, const unsigned* __restrict__ used,
    const float* __restrict__ mse_accum, float* __restrict__ out, int n_elems)
{
    __shared__ float pp[4];
    const int tid = threadIdx.x;
    float s = 0.f;
    for (int k = tid; k < K_CODES; k += TPB)
        if (used[k] == 0u) s += __uint_as_float(minD[k]);
    const int lane = tid & 63;
    const int wid = tid >> 6;
    #pragma unroll
    for (int off = 32; off > 0; off >>= 1) s += __shfl_xor(s, off, 64);
    if (lane == 0) pp[wid] = s;
    __syncthreads();
    if (tid == 0) {
        float ent = (pp[0] + pp[1] + pp[2] + pp[3]) / (float)K_CODES;
        float mse = mse_accum[0] / (float)n_elems;
        // embedding(1.0) + commitment(0.25) share the same value; entropy w=0.1
        out[n_elems] = 1.25f * mse + 0.1f * ent;
    }
}

extern "C" void kernel_launch(void* const* d_in, const int* in_sizes, int n_in,
                              void* d_out, int out_size, void* d_ws, size_t ws_size,
                              hipStream_t stream)
{
    (void)n_in; (void)out_size; (void)ws_size;
    const float* x  = (const float*)d_in[0];
    const float* cb = (const float*)d_in[1];
    float* out = (float*)d_out;
    const int n_elems = in_sizes[0];           // 524288
    const int nrows   = n_elems / D;           // 16384

    unsigned* minD      = (unsigned*)d_ws;
    unsigned* used      = (unsigned*)((char*)d_ws + K_CODES * 4);
    float*    mse_accum = (float*)   ((char*)d_ws + K_CODES * 8);

    hipMemsetAsync(minD, 0x7F, K_CODES * 4, stream);  // 0x7F7F7F7F = 3.39e38 (+inf proxy)
    hipMemsetAsync(used, 0, K_CODES * 4, stream);
    hipMemsetAsync(mse_accum, 0, 4, stream);

    vq_main<<<nrows / ROWS_PB, TPB, 0, stream>>>(x, cb, out, minD, used, mse_accum);
    vq_finish<<<1, TPB, 0, stream>>>(minD, used, mse_accum, out, n_elems);
}